// Round 4
// baseline (374.776 us; speedup 1.0000x reference)
//
#include <hip/hip_runtime.h>
#include <stdint.h>

// B=1024, T=187, H=256, C=5. Fully-fused persistent 2-layer RNN + FC.
// Transposed recurrence: ht = h^T stored in LDS as [batch col][feature],
// so state is the MFMA B-operand and weights (A-operand, f16 fragments)
// stay register-resident. 64 blocks x 16 batch cols, 8 waves/block, each
// wave owns a 32-feature M-slice of all three weight matrices (192 VGPRs).
// Double-buffered state -> 1 barrier/step.
//
// __launch_bounds__(512, 1): R3's (512,2) capped the allocator at 128
// VGPRs -> 25 MB/dispatch of scratch spill traffic in the step loop.
// One 8-wave block per CU needs only 2 waves/SIMD -> 256-VGPR cap, which
// fits the ~250 live registers of the inner loop.

#define Bsz 1024
#define Tt  187
#define Hh  256
#define Cc  5
#define ST  264      // f16 elems per batch-col row (256 + 8 pad)
#define XS  188      // x LDS stride (187 + 1)

typedef _Float16 f16x8 __attribute__((ext_vector_type(8)));
typedef __fp16   fp16x2 __attribute__((ext_vector_type(2)));  // cvt_pkrtz native type
typedef float    f32x4 __attribute__((ext_vector_type(4)));

__device__ __forceinline__ float tanh_fast(float z) {
    float e = __expf(2.0f * z);
    return 1.0f - 2.0f * __builtin_amdgcn_rcpf(1.0f + e);
}

__device__ __forceinline__ unsigned pk2(float a, float b) {
    union { fp16x2 h; unsigned u; } v;
    v.h = __builtin_amdgcn_cvt_pkrtz(a, b);
    return v.u;
}

__global__ __launch_bounds__(512, 1)
void rnn_fused(const float* __restrict__ x,     // [B][T]
               const float* __restrict__ Wih0,  // [H][1]
               const float* __restrict__ Whh0,  // [H][H]
               const float* __restrict__ bih0,
               const float* __restrict__ bhh0,
               const float* __restrict__ Wih1,  // [H][H]
               const float* __restrict__ Whh1,  // [H][H]
               const float* __restrict__ bih1,
               const float* __restrict__ bhh1,
               const float* __restrict__ Wfc,   // [C][H]
               const float* __restrict__ bfc,   // [C]
               float* __restrict__ out)         // [B][C]
{
    __shared__ __align__(16) _Float16 ht0[2][16 * ST];
    __shared__ __align__(16) _Float16 ht1[2][16 * ST];
    __shared__ float xs[16 * XS];

    const int tid  = threadIdx.x;
    const int lane = tid & 63;
    const int w    = tid >> 6;     // wave 0..7 -> features [32w, 32w+32)
    const int q    = lane >> 4;
    const int c    = lane & 15;    // batch col within block
    const int bb   = blockIdx.x * 16;

    // ---- one-time: stage weight A-fragments into registers (f16) ----
    // A-layout: lane (q,c) reg j holds A[m=c][k=kt*32+q*8+j],
    // 8 contiguous elements of row (fb+c).
    f16x8 wh0[2][8], wi1[2][8], wh1[2][8];
    f32x4 b0v[2], b1v[2], wi0v[2];   // per (mt,r): feature fb+4q+r (C/D layout)
#pragma unroll
    for (int mt = 0; mt < 2; ++mt) {
        const int fb = 32 * w + 16 * mt;
#pragma unroll
        for (int r = 0; r < 4; ++r) {
            const int f = fb + 4 * q + r;
            b0v[mt][r]  = bih0[f] + bhh0[f];
            b1v[mt][r]  = bih1[f] + bhh1[f];
            wi0v[mt][r] = Wih0[f];
        }
        const int m = fb + c;
#pragma unroll
        for (int kt = 0; kt < 8; ++kt) {
            const int off = m * Hh + kt * 32 + q * 8;
            {
                const float4 a0 = *(const float4*)(Whh0 + off);
                const float4 a1 = *(const float4*)(Whh0 + off + 4);
                wh0[mt][kt] = (f16x8){(_Float16)a0.x, (_Float16)a0.y, (_Float16)a0.z, (_Float16)a0.w,
                                      (_Float16)a1.x, (_Float16)a1.y, (_Float16)a1.z, (_Float16)a1.w};
            }
            {
                const float4 a0 = *(const float4*)(Wih1 + off);
                const float4 a1 = *(const float4*)(Wih1 + off + 4);
                wi1[mt][kt] = (f16x8){(_Float16)a0.x, (_Float16)a0.y, (_Float16)a0.z, (_Float16)a0.w,
                                      (_Float16)a1.x, (_Float16)a1.y, (_Float16)a1.z, (_Float16)a1.w};
            }
            {
                const float4 a0 = *(const float4*)(Whh1 + off);
                const float4 a1 = *(const float4*)(Whh1 + off + 4);
                wh1[mt][kt] = (f16x8){(_Float16)a0.x, (_Float16)a0.y, (_Float16)a0.z, (_Float16)a0.w,
                                      (_Float16)a1.x, (_Float16)a1.y, (_Float16)a1.z, (_Float16)a1.w};
            }
        }
    }

    // ---- init LDS: x tile, ht1 = 0 (both buffers), ht0[0] = state t=0 ----
    for (int i = tid; i < 16 * Tt; i += 512) {
        const int b = i / Tt, t = i - b * Tt;
        xs[b * XS + t] = x[(bb + b) * Tt + t];
    }
    {
        _Float16* z = &ht1[0][0];
        for (int i = tid; i < 2 * 16 * ST; i += 512) z[i] = (_Float16)0.f;
    }
    for (int i = tid; i < 16 * Hh; i += 512) {
        const int b = i >> 8, f = i & 255;
        const float xv0 = x[(bb + b) * Tt];
        ht0[0][b * ST + f] =
            (_Float16)tanh_fast(xv0 * Wih0[f] + bih0[f] + bhh0[f]);
    }
    __syncthreads();

    // B-operand read base: lane (q,c) reg j needs ht[k=kt*32+q*8+j][col c]
    // -> LDS [c][kt*32+q*8], contiguous 16B (ds_read_b128).
    const int rdoff = c * ST + q * 8;
    const int wroff = c * ST + 32 * w + 4 * q;   // D write: [c][fb+4q .. +3]

    // ---- main recurrence, time-skewed:
    // step s: B0 = ht0[s]; produce ht0[s+1] (Whh0) and ht1[s] (Wih1 + Whh1)
#pragma unroll 1
    for (int s = 0; s < Tt; ++s) {
        const int cur = s & 1, nxt = cur ^ 1;
        const _Float16* B0p = &ht0[cur][rdoff];
        const _Float16* B1p = &ht1[nxt][rdoff];   // ht1[s-1]
        int sn = s + 1; if (sn >= Tt) sn = Tt - 1;  // last h0_next unused
        const float xv = xs[c * XS + sn];

        // layer0: ai = Wih1 . ht0 + b1 ; ah0 = Whh0 . ht0 + b0 (shared B-frag)
        f32x4 ai[2], ah0[2];
        {
            const f16x8 B = *(const f16x8*)B0p;
            ai[0]  = __builtin_amdgcn_mfma_f32_16x16x32_f16(wi1[0][0], B, b1v[0], 0, 0, 0);
            ai[1]  = __builtin_amdgcn_mfma_f32_16x16x32_f16(wi1[1][0], B, b1v[1], 0, 0, 0);
            ah0[0] = __builtin_amdgcn_mfma_f32_16x16x32_f16(wh0[0][0], B, b0v[0], 0, 0, 0);
            ah0[1] = __builtin_amdgcn_mfma_f32_16x16x32_f16(wh0[1][0], B, b0v[1], 0, 0, 0);
        }
#pragma unroll
        for (int kt = 1; kt < 8; ++kt) {
            const f16x8 B = *(const f16x8*)(B0p + kt * 32);
            ai[0]  = __builtin_amdgcn_mfma_f32_16x16x32_f16(wi1[0][kt], B, ai[0],  0, 0, 0);
            ai[1]  = __builtin_amdgcn_mfma_f32_16x16x32_f16(wi1[1][kt], B, ai[1],  0, 0, 0);
            ah0[0] = __builtin_amdgcn_mfma_f32_16x16x32_f16(wh0[0][kt], B, ah0[0], 0, 0, 0);
            ah0[1] = __builtin_amdgcn_mfma_f32_16x16x32_f16(wh0[1][kt], B, ah0[1], 0, 0, 0);
        }
        // ht0[s+1] = tanh(ah0 + x_{s+1} * wih0), pack f16, 8B LDS writes
#pragma unroll
        for (int mt = 0; mt < 2; ++mt) {
            const float t0 = tanh_fast(ah0[mt][0] + xv * wi0v[mt][0]);
            const float t1 = tanh_fast(ah0[mt][1] + xv * wi0v[mt][1]);
            const float t2 = tanh_fast(ah0[mt][2] + xv * wi0v[mt][2]);
            const float t3 = tanh_fast(ah0[mt][3] + xv * wi0v[mt][3]);
            *(uint2*)(&ht0[nxt][wroff + 16 * mt]) = make_uint2(pk2(t0, t1), pk2(t2, t3));
        }

        // layer1: ah1 = Whh1 . ht1[s-1]
        f32x4 ah1[2];
        {
            const f16x8 B = *(const f16x8*)B1p;
            const f32x4 z4 = (f32x4){0.f, 0.f, 0.f, 0.f};
            ah1[0] = __builtin_amdgcn_mfma_f32_16x16x32_f16(wh1[0][0], B, z4, 0, 0, 0);
            ah1[1] = __builtin_amdgcn_mfma_f32_16x16x32_f16(wh1[1][0], B, z4, 0, 0, 0);
        }
#pragma unroll
        for (int kt = 1; kt < 8; ++kt) {
            const f16x8 B = *(const f16x8*)(B1p + kt * 32);
            ah1[0] = __builtin_amdgcn_mfma_f32_16x16x32_f16(wh1[0][kt], B, ah1[0], 0, 0, 0);
            ah1[1] = __builtin_amdgcn_mfma_f32_16x16x32_f16(wh1[1][kt], B, ah1[1], 0, 0, 0);
        }
        // ht1[s] = tanh(ai + ah1)
#pragma unroll
        for (int mt = 0; mt < 2; ++mt) {
            const float t0 = tanh_fast(ai[mt][0] + ah1[mt][0]);
            const float t1 = tanh_fast(ai[mt][1] + ah1[mt][1]);
            const float t2 = tanh_fast(ai[mt][2] + ah1[mt][2]);
            const float t3 = tanh_fast(ai[mt][3] + ah1[mt][3]);
            *(uint2*)(&ht1[cur][wroff + 16 * mt]) = make_uint2(pk2(t0, t1), pk2(t2, t3));
        }
        __syncthreads();   // double-buffered: one barrier per step
    }

    // ---- FC epilogue: out[bb+b][cls] = ht1_final[.][b] . Wfc[cls] + bfc ----
    if (tid < 16 * Cc) {
        const int b = tid / Cc, cls = tid - Cc * (tid / Cc);
        const _Float16* h = &ht1[(Tt - 1) & 1][b * ST];
        float acc = bfc[cls];
        for (int k = 0; k < Hh; ++k)
            acc += (float)h[k] * Wfc[cls * Hh + k];
        out[(bb + b) * Cc + cls] = acc;
    }
}

extern "C" void kernel_launch(void* const* d_in, const int* in_sizes, int n_in,
                              void* d_out, int out_size, void* d_ws, size_t ws_size,
                              hipStream_t stream) {
    rnn_fused<<<dim3(Bsz / 16), dim3(512), 0, stream>>>(
        (const float*)d_in[0],  // x
        (const float*)d_in[1],  // W_ih0
        (const float*)d_in[2],  // W_hh0
        (const float*)d_in[3],  // b_ih0
        (const float*)d_in[4],  // b_hh0
        (const float*)d_in[5],  // W_ih1
        (const float*)d_in[6],  // W_hh1
        (const float*)d_in[7],  // b_ih1
        (const float*)d_in[8],  // b_hh1
        (const float*)d_in[9],  // W_fc
        (const float*)d_in[10], // b_fc
        (float*)d_out);
}

// Round 5
// 349.664 us; speedup vs baseline: 1.0718x; 1.0718x over previous
//
#include <hip/hip_runtime.h>
#include <stdint.h>

// B=1024, T=187, H=256, C=5. Fully-fused persistent 2-layer RNN + FC.
// Transposed recurrence: ht = h^T stored in LDS as [batch col][feature],
// so state is the MFMA B-operand and weights (A-operand, f16 fragments)
// stay register-resident. 64 blocks x 16 batch cols, 8 waves/block, each
// wave owns a 32-feature M-slice. Double-buffered state -> 1 barrier/step.
//
// R3/R4 lesson: launch_bounds 2nd arg is a MIN waves/EU — allocator still
// chose 4 waves/EU -> 128-VGPR cap -> 25 MB/step-loop spill traffic.
// Fix: amdgpu_waves_per_eu(2,2) pins occupancy to 2 waves/EU (cap 256),
// and the kt>=4 half of Whh1 lives in per-wave-private LDS (saves 64
// VGPRs) so the loop's ~226 live regs fit under 256 with slack.

#define Bsz 1024
#define Tt  187
#define Hh  256
#define Cc  5
#define ST  264      // f16 elems per batch-col row (256 + 8 pad)
#define XS  188      // x LDS stride (187 + 1)

typedef _Float16 f16x8 __attribute__((ext_vector_type(8)));
typedef __fp16   fp16x2 __attribute__((ext_vector_type(2)));  // cvt_pkrtz native type
typedef float    f32x4 __attribute__((ext_vector_type(4)));

__device__ __forceinline__ float tanh_fast(float z) {
    float e = __expf(2.0f * z);
    return 1.0f - 2.0f * __builtin_amdgcn_rcpf(1.0f + e);
}

__device__ __forceinline__ unsigned pk2(float a, float b) {
    union { fp16x2 h; unsigned u; } v;
    v.h = __builtin_amdgcn_cvt_pkrtz(a, b);
    return v.u;
}

__global__ __launch_bounds__(512) __attribute__((amdgpu_waves_per_eu(2, 2)))
void rnn_fused(const float* __restrict__ x,     // [B][T]
               const float* __restrict__ Wih0,  // [H][1]
               const float* __restrict__ Whh0,  // [H][H]
               const float* __restrict__ bih0,
               const float* __restrict__ bhh0,
               const float* __restrict__ Wih1,  // [H][H]
               const float* __restrict__ Whh1,  // [H][H]
               const float* __restrict__ bih1,
               const float* __restrict__ bhh1,
               const float* __restrict__ Wfc,   // [C][H]
               const float* __restrict__ bfc,   // [C]
               float* __restrict__ out)         // [B][C]
{
    __shared__ __align__(16) _Float16 ht0[2][16 * ST];
    __shared__ __align__(16) _Float16 ht1[2][16 * ST];
    __shared__ float xs[16 * XS];
    __shared__ f16x8 w1lds[8][2][4][64];   // Whh1 kt=4..7 fragments, per-wave private

    const int tid  = threadIdx.x;
    const int lane = tid & 63;
    const int w    = tid >> 6;     // wave 0..7 -> features [32w, 32w+32)
    const int q    = lane >> 4;
    const int c    = lane & 15;    // batch col within block
    const int bb   = blockIdx.x * 16;

    // ---- one-time: stage weight A-fragments (f16) ----
    // A-layout: lane (q,c) reg j holds A[m=c][k=kt*32+q*8+j],
    // 8 contiguous elements of row (fb+c).
    f16x8 wh0[2][8], wi1[2][8], wh1r[2][4];
    f32x4 b0v[2], b1v[2], wi0v[2];   // per (mt,r): feature fb+4q+r (C/D layout)
#pragma unroll
    for (int mt = 0; mt < 2; ++mt) {
        const int fb = 32 * w + 16 * mt;
#pragma unroll
        for (int r = 0; r < 4; ++r) {
            const int f = fb + 4 * q + r;
            b0v[mt][r]  = bih0[f] + bhh0[f];
            b1v[mt][r]  = bih1[f] + bhh1[f];
            wi0v[mt][r] = Wih0[f];
        }
        const int m = fb + c;
#pragma unroll
        for (int kt = 0; kt < 8; ++kt) {
            const int off = m * Hh + kt * 32 + q * 8;
            {
                const float4 a0 = *(const float4*)(Whh0 + off);
                const float4 a1 = *(const float4*)(Whh0 + off + 4);
                wh0[mt][kt] = (f16x8){(_Float16)a0.x, (_Float16)a0.y, (_Float16)a0.z, (_Float16)a0.w,
                                      (_Float16)a1.x, (_Float16)a1.y, (_Float16)a1.z, (_Float16)a1.w};
            }
            {
                const float4 a0 = *(const float4*)(Wih1 + off);
                const float4 a1 = *(const float4*)(Wih1 + off + 4);
                wi1[mt][kt] = (f16x8){(_Float16)a0.x, (_Float16)a0.y, (_Float16)a0.z, (_Float16)a0.w,
                                      (_Float16)a1.x, (_Float16)a1.y, (_Float16)a1.z, (_Float16)a1.w};
            }
            {
                const float4 a0 = *(const float4*)(Whh1 + off);
                const float4 a1 = *(const float4*)(Whh1 + off + 4);
                f16x8 f = (f16x8){(_Float16)a0.x, (_Float16)a0.y, (_Float16)a0.z, (_Float16)a0.w,
                                  (_Float16)a1.x, (_Float16)a1.y, (_Float16)a1.z, (_Float16)a1.w};
                if (kt < 4) wh1r[mt][kt] = f;
                else        w1lds[w][mt][kt - 4][lane] = f;
            }
        }
    }

    // ---- init LDS: x tile, ht1 = 0 (both buffers), ht0[0] = state t=0 ----
    for (int i = tid; i < 16 * Tt; i += 512) {
        const int b = i / Tt, t = i - b * Tt;
        xs[b * XS + t] = x[(bb + b) * Tt + t];
    }
    {
        _Float16* z = &ht1[0][0];
        for (int i = tid; i < 2 * 16 * ST; i += 512) z[i] = (_Float16)0.f;
    }
    for (int i = tid; i < 16 * Hh; i += 512) {
        const int b = i >> 8, f = i & 255;
        const float xv0 = x[(bb + b) * Tt];
        ht0[0][b * ST + f] =
            (_Float16)tanh_fast(xv0 * Wih0[f] + bih0[f] + bhh0[f]);
    }
    __syncthreads();   // also makes w1lds visible (wave-private anyway)

    // B-operand read base: lane (q,c) reg j needs ht[k=kt*32+q*8+j][col c]
    // -> LDS [c][kt*32+q*8], contiguous 16B (ds_read_b128).
    const int rdoff = c * ST + q * 8;
    const int wroff = c * ST + 32 * w + 4 * q;   // D write: [c][fb+4q .. +3]

    // ---- main recurrence, time-skewed:
    // step s: B0 = ht0[s]; produce ht0[s+1] (Whh0) and ht1[s] (Wih1 + Whh1)
#pragma unroll 1
    for (int s = 0; s < Tt; ++s) {
        const int cur = s & 1, nxt = cur ^ 1;
        const _Float16* B0p = &ht0[cur][rdoff];
        const _Float16* B1p = &ht1[nxt][rdoff];   // ht1[s-1]
        int sn = s + 1; if (sn >= Tt) sn = Tt - 1;  // last h0_next unused
        const float xv = xs[c * XS + sn];

        // layer0: ai = Wih1 . ht0 + b1 ; ah0 = Whh0 . ht0 + b0 (shared B-frag)
        f32x4 ai[2], ah0[2];
        {
            const f16x8 B = *(const f16x8*)B0p;
            ai[0]  = __builtin_amdgcn_mfma_f32_16x16x32_f16(wi1[0][0], B, b1v[0], 0, 0, 0);
            ai[1]  = __builtin_amdgcn_mfma_f32_16x16x32_f16(wi1[1][0], B, b1v[1], 0, 0, 0);
            ah0[0] = __builtin_amdgcn_mfma_f32_16x16x32_f16(wh0[0][0], B, b0v[0], 0, 0, 0);
            ah0[1] = __builtin_amdgcn_mfma_f32_16x16x32_f16(wh0[1][0], B, b0v[1], 0, 0, 0);
        }
#pragma unroll
        for (int kt = 1; kt < 8; ++kt) {
            const f16x8 B = *(const f16x8*)(B0p + kt * 32);
            ai[0]  = __builtin_amdgcn_mfma_f32_16x16x32_f16(wi1[0][kt], B, ai[0],  0, 0, 0);
            ai[1]  = __builtin_amdgcn_mfma_f32_16x16x32_f16(wi1[1][kt], B, ai[1],  0, 0, 0);
            ah0[0] = __builtin_amdgcn_mfma_f32_16x16x32_f16(wh0[0][kt], B, ah0[0], 0, 0, 0);
            ah0[1] = __builtin_amdgcn_mfma_f32_16x16x32_f16(wh0[1][kt], B, ah0[1], 0, 0, 0);
        }
        // ht0[s+1] = tanh(ah0 + x_{s+1} * wih0), pack f16, 8B LDS writes
#pragma unroll
        for (int mt = 0; mt < 2; ++mt) {
            const float t0 = tanh_fast(ah0[mt][0] + xv * wi0v[mt][0]);
            const float t1 = tanh_fast(ah0[mt][1] + xv * wi0v[mt][1]);
            const float t2 = tanh_fast(ah0[mt][2] + xv * wi0v[mt][2]);
            const float t3 = tanh_fast(ah0[mt][3] + xv * wi0v[mt][3]);
            *(uint2*)(&ht0[nxt][wroff + 16 * mt]) = make_uint2(pk2(t0, t1), pk2(t2, t3));
        }

        // layer1: ah1 = Whh1 . ht1[s-1]; kt<4 weights in regs, kt>=4 from LDS
        f32x4 ah1[2];
        {
            const f16x8 B = *(const f16x8*)B1p;
            const f32x4 z4 = (f32x4){0.f, 0.f, 0.f, 0.f};
            ah1[0] = __builtin_amdgcn_mfma_f32_16x16x32_f16(wh1r[0][0], B, z4, 0, 0, 0);
            ah1[1] = __builtin_amdgcn_mfma_f32_16x16x32_f16(wh1r[1][0], B, z4, 0, 0, 0);
        }
#pragma unroll
        for (int kt = 1; kt < 4; ++kt) {
            const f16x8 B = *(const f16x8*)(B1p + kt * 32);
            ah1[0] = __builtin_amdgcn_mfma_f32_16x16x32_f16(wh1r[0][kt], B, ah1[0], 0, 0, 0);
            ah1[1] = __builtin_amdgcn_mfma_f32_16x16x32_f16(wh1r[1][kt], B, ah1[1], 0, 0, 0);
        }
#pragma unroll
        for (int kt = 4; kt < 8; ++kt) {
            const f16x8 B  = *(const f16x8*)(B1p + kt * 32);
            const f16x8 A0 = w1lds[w][0][kt - 4][lane];
            const f16x8 A1 = w1lds[w][1][kt - 4][lane];
            ah1[0] = __builtin_amdgcn_mfma_f32_16x16x32_f16(A0, B, ah1[0], 0, 0, 0);
            ah1[1] = __builtin_amdgcn_mfma_f32_16x16x32_f16(A1, B, ah1[1], 0, 0, 0);
        }
        // ht1[s] = tanh(ai + ah1)
#pragma unroll
        for (int mt = 0; mt < 2; ++mt) {
            const float t0 = tanh_fast(ai[mt][0] + ah1[mt][0]);
            const float t1 = tanh_fast(ai[mt][1] + ah1[mt][1]);
            const float t2 = tanh_fast(ai[mt][2] + ah1[mt][2]);
            const float t3 = tanh_fast(ai[mt][3] + ah1[mt][3]);
            *(uint2*)(&ht1[cur][wroff + 16 * mt]) = make_uint2(pk2(t0, t1), pk2(t2, t3));
        }
        __syncthreads();   // double-buffered: one barrier per step
    }

    // ---- FC epilogue: out[bb+b][cls] = ht1_final[.][b] . Wfc[cls] + bfc ----
    if (tid < 16 * Cc) {
        const int b = tid / Cc, cls = tid - Cc * (tid / Cc);
        const _Float16* h = &ht1[(Tt - 1) & 1][b * ST];
        float acc = bfc[cls];
        for (int k = 0; k < Hh; ++k)
            acc += (float)h[k] * Wfc[cls * Hh + k];
        out[(bb + b) * Cc + cls] = acc;
    }
}

extern "C" void kernel_launch(void* const* d_in, const int* in_sizes, int n_in,
                              void* d_out, int out_size, void* d_ws, size_t ws_size,
                              hipStream_t stream) {
    rnn_fused<<<dim3(Bsz / 16), dim3(512), 0, stream>>>(
        (const float*)d_in[0],  // x
        (const float*)d_in[1],  // W_ih0
        (const float*)d_in[2],  // W_hh0
        (const float*)d_in[3],  // b_ih0
        (const float*)d_in[4],  // b_hh0
        (const float*)d_in[5],  // W_ih1
        (const float*)d_in[6],  // W_hh1
        (const float*)d_in[7],  // b_ih1
        (const float*)d_in[8],  // b_hh1
        (const float*)d_in[9],  // W_fc
        (const float*)d_in[10], // b_fc
        (float*)d_out);
}

// Round 6
// 347.819 us; speedup vs baseline: 1.0775x; 1.0053x over previous
//
#include <hip/hip_runtime.h>
#include <stdint.h>

// B=1024, T=187, H=256, C=5. Fully-fused persistent 2-layer RNN + FC.
// Transposed recurrence: ht = h^T stored in LDS as [batch col][feature],
// so state is the MFMA B-operand and weights (A-operand, f16 fragments)
// stay register-resident. 64 blocks x 16 batch cols, 8 waves/block, each
// wave owns a 32-feature M-slice. Double-buffered state -> 1 barrier/step.
//
// R3-R5 lesson: the __launch_bounds__ macro path left the allocator at a
// 128-VGPR budget (4 waves/EU target) -> scratch spills every step
// (15-25 MB HBM writeback/dispatch). R6: bypass the macro, pin occupancy
// directly with amdgpu_flat_work_group_size(512,512) +
// amdgpu_waves_per_eu(2,2) -> 256-VGPR budget; inner loop needs ~190
// (Whh1 kt>=4 half lives in per-wave-private LDS) and fits with slack.

#define Bsz 1024
#define Tt  187
#define Hh  256
#define Cc  5
#define ST  264      // f16 elems per batch-col row (256 + 8 pad; 2-way bank alias only)
#define XS  188      // x LDS stride (187 + 1)

typedef _Float16 f16x8 __attribute__((ext_vector_type(8)));
typedef __fp16   fp16x2 __attribute__((ext_vector_type(2)));  // cvt_pkrtz native type
typedef float    f32x4 __attribute__((ext_vector_type(4)));

__device__ __forceinline__ float tanh_fast(float z) {
    float e = __expf(2.0f * z);
    return 1.0f - 2.0f * __builtin_amdgcn_rcpf(1.0f + e);
}

__device__ __forceinline__ unsigned pk2(float a, float b) {
    union { fp16x2 h; unsigned u; } v;
    v.h = __builtin_amdgcn_cvt_pkrtz(a, b);
    return v.u;
}

__global__ __attribute__((amdgpu_flat_work_group_size(512, 512), amdgpu_waves_per_eu(2, 2)))
void rnn_fused(const float* __restrict__ x,     // [B][T]
               const float* __restrict__ Wih0,  // [H][1]
               const float* __restrict__ Whh0,  // [H][H]
               const float* __restrict__ bih0,
               const float* __restrict__ bhh0,
               const float* __restrict__ Wih1,  // [H][H]
               const float* __restrict__ Whh1,  // [H][H]
               const float* __restrict__ bih1,
               const float* __restrict__ bhh1,
               const float* __restrict__ Wfc,   // [C][H]
               const float* __restrict__ bfc,   // [C]
               float* __restrict__ out)         // [B][C]
{
    __shared__ __align__(16) _Float16 ht0[2][16 * ST];
    __shared__ __align__(16) _Float16 ht1[2][16 * ST];
    __shared__ float xs[16 * XS];
    __shared__ f16x8 w1lds[8][2][4][64];   // Whh1 kt=4..7 fragments, per-wave private

    const int tid  = threadIdx.x;
    const int lane = tid & 63;
    const int w    = tid >> 6;     // wave 0..7 -> features [32w, 32w+32)
    const int q    = lane >> 4;
    const int c    = lane & 15;    // batch col within block
    const int bb   = blockIdx.x * 16;

    // ---- one-time: stage weight A-fragments (f16) ----
    // A-layout: lane (q,c) reg j holds A[m=c][k=kt*32+q*8+j],
    // 8 contiguous elements of row (fb+c).
    f16x8 wh0[2][8], wi1[2][8], wh1r[2][4];
    f32x4 b0v[2], b1v[2], wi0v[2];   // per (mt,r): feature fb+4q+r (C/D layout)
#pragma unroll
    for (int mt = 0; mt < 2; ++mt) {
        const int fb = 32 * w + 16 * mt;
#pragma unroll
        for (int r = 0; r < 4; ++r) {
            const int f = fb + 4 * q + r;
            b0v[mt][r]  = bih0[f] + bhh0[f];
            b1v[mt][r]  = bih1[f] + bhh1[f];
            wi0v[mt][r] = Wih0[f];
        }
        const int m = fb + c;
#pragma unroll
        for (int kt = 0; kt < 8; ++kt) {
            const int off = m * Hh + kt * 32 + q * 8;
            {
                const float4 a0 = *(const float4*)(Whh0 + off);
                const float4 a1 = *(const float4*)(Whh0 + off + 4);
                wh0[mt][kt] = (f16x8){(_Float16)a0.x, (_Float16)a0.y, (_Float16)a0.z, (_Float16)a0.w,
                                      (_Float16)a1.x, (_Float16)a1.y, (_Float16)a1.z, (_Float16)a1.w};
            }
            {
                const float4 a0 = *(const float4*)(Wih1 + off);
                const float4 a1 = *(const float4*)(Wih1 + off + 4);
                wi1[mt][kt] = (f16x8){(_Float16)a0.x, (_Float16)a0.y, (_Float16)a0.z, (_Float16)a0.w,
                                      (_Float16)a1.x, (_Float16)a1.y, (_Float16)a1.z, (_Float16)a1.w};
            }
            {
                const float4 a0 = *(const float4*)(Whh1 + off);
                const float4 a1 = *(const float4*)(Whh1 + off + 4);
                f16x8 f = (f16x8){(_Float16)a0.x, (_Float16)a0.y, (_Float16)a0.z, (_Float16)a0.w,
                                  (_Float16)a1.x, (_Float16)a1.y, (_Float16)a1.z, (_Float16)a1.w};
                if (kt < 4) wh1r[mt][kt] = f;
                else        w1lds[w][mt][kt - 4][lane] = f;
            }
        }
    }

    // ---- init LDS: x tile, ht1 = 0 (both buffers), ht0[0] = state t=0 ----
    for (int i = tid; i < 16 * Tt; i += 512) {
        const int b = i / Tt, t = i - b * Tt;
        xs[b * XS + t] = x[(bb + b) * Tt + t];
    }
    {
        _Float16* z = &ht1[0][0];
        for (int i = tid; i < 2 * 16 * ST; i += 512) z[i] = (_Float16)0.f;
    }
    for (int i = tid; i < 16 * Hh; i += 512) {
        const int b = i >> 8, f = i & 255;
        const float xv0 = x[(bb + b) * Tt];
        ht0[0][b * ST + f] =
            (_Float16)tanh_fast(xv0 * Wih0[f] + bih0[f] + bhh0[f]);
    }
    __syncthreads();   // also makes w1lds visible (wave-private anyway)

    // B-operand read base: lane (q,c) reg j needs ht[k=kt*32+q*8+j][col c]
    // -> LDS [c][kt*32+q*8], contiguous 16B (ds_read_b128).
    const int rdoff = c * ST + q * 8;
    const int wroff = c * ST + 32 * w + 4 * q;   // D write: [c][fb+4q .. +3]

    // ---- main recurrence, time-skewed:
    // step s: B0 = ht0[s]; produce ht0[s+1] (Whh0) and ht1[s] (Wih1 + Whh1)
#pragma unroll 1
    for (int s = 0; s < Tt; ++s) {
        const int cur = s & 1, nxt = cur ^ 1;
        const _Float16* B0p = &ht0[cur][rdoff];
        const _Float16* B1p = &ht1[nxt][rdoff];   // ht1[s-1]
        int sn = s + 1; if (sn >= Tt) sn = Tt - 1;  // last h0_next unused
        const float xv = xs[c * XS + sn];

        // layer0: ai = Wih1 . ht0 + b1 ; ah0 = Whh0 . ht0 + b0 (shared B-frag)
        f32x4 ai[2], ah0[2];
        {
            const f16x8 B = *(const f16x8*)B0p;
            ai[0]  = __builtin_amdgcn_mfma_f32_16x16x32_f16(wi1[0][0], B, b1v[0], 0, 0, 0);
            ai[1]  = __builtin_amdgcn_mfma_f32_16x16x32_f16(wi1[1][0], B, b1v[1], 0, 0, 0);
            ah0[0] = __builtin_amdgcn_mfma_f32_16x16x32_f16(wh0[0][0], B, b0v[0], 0, 0, 0);
            ah0[1] = __builtin_amdgcn_mfma_f32_16x16x32_f16(wh0[1][0], B, b0v[1], 0, 0, 0);
        }
#pragma unroll
        for (int kt = 1; kt < 8; ++kt) {
            const f16x8 B = *(const f16x8*)(B0p + kt * 32);
            ai[0]  = __builtin_amdgcn_mfma_f32_16x16x32_f16(wi1[0][kt], B, ai[0],  0, 0, 0);
            ai[1]  = __builtin_amdgcn_mfma_f32_16x16x32_f16(wi1[1][kt], B, ai[1],  0, 0, 0);
            ah0[0] = __builtin_amdgcn_mfma_f32_16x16x32_f16(wh0[0][kt], B, ah0[0], 0, 0, 0);
            ah0[1] = __builtin_amdgcn_mfma_f32_16x16x32_f16(wh0[1][kt], B, ah0[1], 0, 0, 0);
        }
        // ht0[s+1] = tanh(ah0 + x_{s+1} * wih0), pack f16, 8B LDS writes
#pragma unroll
        for (int mt = 0; mt < 2; ++mt) {
            const float t0 = tanh_fast(ah0[mt][0] + xv * wi0v[mt][0]);
            const float t1 = tanh_fast(ah0[mt][1] + xv * wi0v[mt][1]);
            const float t2 = tanh_fast(ah0[mt][2] + xv * wi0v[mt][2]);
            const float t3 = tanh_fast(ah0[mt][3] + xv * wi0v[mt][3]);
            *(uint2*)(&ht0[nxt][wroff + 16 * mt]) = make_uint2(pk2(t0, t1), pk2(t2, t3));
        }

        // layer1: ah1 = Whh1 . ht1[s-1]; kt<4 weights in regs, kt>=4 from LDS
        f32x4 ah1[2];
        {
            const f16x8 B = *(const f16x8*)B1p;
            const f32x4 z4 = (f32x4){0.f, 0.f, 0.f, 0.f};
            ah1[0] = __builtin_amdgcn_mfma_f32_16x16x32_f16(wh1r[0][0], B, z4, 0, 0, 0);
            ah1[1] = __builtin_amdgcn_mfma_f32_16x16x32_f16(wh1r[1][0], B, z4, 0, 0, 0);
        }
#pragma unroll
        for (int kt = 1; kt < 4; ++kt) {
            const f16x8 B = *(const f16x8*)(B1p + kt * 32);
            ah1[0] = __builtin_amdgcn_mfma_f32_16x16x32_f16(wh1r[0][kt], B, ah1[0], 0, 0, 0);
            ah1[1] = __builtin_amdgcn_mfma_f32_16x16x32_f16(wh1r[1][kt], B, ah1[1], 0, 0, 0);
        }
#pragma unroll
        for (int kt = 4; kt < 8; ++kt) {
            const f16x8 B  = *(const f16x8*)(B1p + kt * 32);
            const f16x8 A0 = w1lds[w][0][kt - 4][lane];
            const f16x8 A1 = w1lds[w][1][kt - 4][lane];
            ah1[0] = __builtin_amdgcn_mfma_f32_16x16x32_f16(A0, B, ah1[0], 0, 0, 0);
            ah1[1] = __builtin_amdgcn_mfma_f32_16x16x32_f16(A1, B, ah1[1], 0, 0, 0);
        }
        // ht1[s] = tanh(ai + ah1)
#pragma unroll
        for (int mt = 0; mt < 2; ++mt) {
            const float t0 = tanh_fast(ai[mt][0] + ah1[mt][0]);
            const float t1 = tanh_fast(ai[mt][1] + ah1[mt][1]);
            const float t2 = tanh_fast(ai[mt][2] + ah1[mt][2]);
            const float t3 = tanh_fast(ai[mt][3] + ah1[mt][3]);
            *(uint2*)(&ht1[cur][wroff + 16 * mt]) = make_uint2(pk2(t0, t1), pk2(t2, t3));
        }
        __syncthreads();   // double-buffered: one barrier per step
    }

    // ---- FC epilogue: out[bb+b][cls] = ht1_final[.][b] . Wfc[cls] + bfc ----
    if (tid < 16 * Cc) {
        const int b = tid / Cc, cls = tid - Cc * (tid / Cc);
        const _Float16* h = &ht1[(Tt - 1) & 1][b * ST];
        float acc = bfc[cls];
        for (int k = 0; k < Hh; ++k)
            acc += (float)h[k] * Wfc[cls * Hh + k];
        out[(bb + b) * Cc + cls] = acc;
    }
}

extern "C" void kernel_launch(void* const* d_in, const int* in_sizes, int n_in,
                              void* d_out, int out_size, void* d_ws, size_t ws_size,
                              hipStream_t stream) {
    rnn_fused<<<dim3(Bsz / 16), dim3(512), 0, stream>>>(
        (const float*)d_in[0],  // x
        (const float*)d_in[1],  // W_ih0
        (const float*)d_in[2],  // W_hh0
        (const float*)d_in[3],  // b_ih0
        (const float*)d_in[4],  // b_hh0
        (const float*)d_in[5],  // W_ih1
        (const float*)d_in[6],  // W_hh1
        (const float*)d_in[7],  // b_ih1
        (const float*)d_in[8],  // b_hh1
        (const float*)d_in[9],  // W_fc
        (const float*)d_in[10], // b_fc
        (float*)d_out);
}